// Round 12
// baseline (103.268 us; speedup 1.0000x reference)
//
#include <hip/hip_runtime.h>

#define IN_F     512
#define OUT_F    10240
#define NPROJ    6
#define THREADS  512
#define PER_T    (OUT_F / THREADS)   // 20 outputs per thread
#define ROWS     4                   // batch rows per block
#define NBINS    256
#define CAND_CAP 128
#define NWAVES   (THREADS / 64)
#define BIN_OFF  8064u               // (bits>>17) of 0.5f

typedef float    float4v __attribute__((ext_vector_type(4)));
typedef unsigned uint4v  __attribute__((ext_vector_type(4)));

// Raw barrier that drains LDS ops only: global stores stay in flight
// (hipcc's __syncthreads lowers to s_waitcnt vmcnt(0) lgkmcnt(0) + s_barrier,
// which would serialize the early bulk store against the select tail).
__device__ __forceinline__ void bar_nodrain() {
    asm volatile("s_waitcnt lgkmcnt(0)" ::: "memory");
    __builtin_amdgcn_s_barrier();
    __builtin_amdgcn_sched_barrier(0);
}

// One block = 4 batch rows (round-10 selection math, restructured stores).
//  gather -> thread-max static-bit histogram -> (all-wave ballot scan: B,T4)
//  -> EARLY bulk store of provable zeros (v < T4 <= kth), candidates skipped
//  -> collect candidates -> rank select / bisection -> fixup stores candidates.
// Every output address is written exactly once per call (bulk XOR fixup).
__global__ __launch_bounds__(THREADS, 4) void flyhash_wta_kernel(
    const float* __restrict__ inp,
    const int*   __restrict__ proj,
    const int*   __restrict__ hlen,
    float*       __restrict__ out,
    int batch)
{
    __shared__ float4v  s_rowT[IN_F];             // 8 KB transposed tile
    __shared__ unsigned s_hist[ROWS][NBINS];      // 4 KB thread-max histogram
    __shared__ float    s_cand[ROWS][CAND_CAP];   // 2 KB
    __shared__ unsigned s_cnt[ROWS];
    __shared__ float    s_kth[ROWS];
    __shared__ int      s_pc[ROWS][NWAVES];       // bisection partial counts

    const int t    = threadIdx.x;
    const int lane = t & 63;
    const int wave = t >> 6;
    const int b0   = blockIdx.x * ROWS;

    // --- stage 4 rows transposed (linear LDS writes); zero select state ---
    {
        const int r  = t & 3;
        const int cb = t >> 2;
        int br = b0 + r;
        if (br >= batch) br = batch - 1;           // clamp (reads only)
        const float* g = inp + (size_t)br * IN_F;
#pragma unroll
        for (int p = 0; p < 4; ++p) {
            const int c = cb + p * (THREADS / 4);
            ((float*)s_rowT)[c * 4 + r] = g[c];
        }
    }
    ((unsigned*)s_hist)[t]           = 0u;
    ((unsigned*)s_hist)[t + THREADS] = 0u;
    if (t < ROWS) { s_cnt[t] = 0u; s_kth[t] = 0.0f; }
    __syncthreads();                               // A (no stores in flight)

    const int k0 = hlen[0];

    // --- gather: one ds_read_b128 per index serves all 4 rows ---
    float4v acc[PER_T];
#pragma unroll
    for (int i = 0; i < PER_T; ++i) {
        const int o = t + i * THREADS;
        const int2* ip = (const int2*)(proj + (size_t)o * NPROJ);
        const int2 p0 = ip[0];
        const int2 p1 = ip[1];
        const int2 p2 = ip[2];
        // same per-component summation order as rounds 1-11 (absmax 0)
        const float4v a01 = s_rowT[p0.x] + s_rowT[p0.y];
        const float4v a23 = s_rowT[p1.x] + s_rowT[p1.y];
        const float4v a45 = s_rowT[p2.x] + s_rowT[p2.y];
        acc[i] = (a01 + a23) + a45;
    }

    // --- per-thread per-row max ---
    float4v tmax = acc[0];
#pragma unroll
    for (int i = 1; i < PER_T; ++i) {
        tmax.x = fmaxf(tmax.x, acc[i].x);
        tmax.y = fmaxf(tmax.y, acc[i].y);
        tmax.z = fmaxf(tmax.z, acc[i].z);
        tmax.w = fmaxf(tmax.w, acc[i].w);
    }

    // --- static-bit histogram of thread-maxes: 4 atomics/thread ---
#pragma unroll
    for (int r = 0; r < ROWS; ++r) {
        int key = (int)(__float_as_uint(tmax[r]) >> 17) - (int)BIN_OFF;
        key = key < 0 ? 0 : (key > NBINS - 1 ? NBINS - 1 : key);
        atomicAdd(&s_hist[r][key], 1u);
    }
    __syncthreads();                               // B (no stores in flight)

    // --- ALL-wave redundant suffix scan + ballot bin-find: no broadcast
    //     barrier; every thread gets T4[r] locally, stores can issue now ---
    float4v T4;
#pragma unroll
    for (int r = 0; r < ROWS; ++r) {
        const uint4v h = ((const uint4v*)&s_hist[r][0])[lane];
        const unsigned s3 = h.w;
        const unsigned s2 = h.z + s3;
        const unsigned s1 = h.y + s2;
        const unsigned s0 = h.x + s1;
        unsigned T = s0;
#pragma unroll
        for (int d = 1; d < 64; d <<= 1) {
            const unsigned o = __shfl_down(T, d);
            if (lane + d < 64) T += o;
        }
        const unsigned A = T - s0;                 // sum over lanes > lane
        const unsigned S0 = A + s0, S1 = A + s1, S2 = A + s2, S3 = A + s3;
        const bool cx = h.x && (int)S0 >= k0 && (int)(S0 - h.x) < k0;
        const bool cy = h.y && (int)S1 >= k0 && (int)(S1 - h.y) < k0;
        const bool cz = h.z && (int)S2 >= k0 && (int)(S2 - h.z) < k0;
        const bool cw = h.w && (int)S3 >= k0 && (int)(S3 - h.w) < k0;
        const unsigned long long bx = __ballot(cx);
        const unsigned long long by = __ballot(cy);
        const unsigned long long bz = __ballot(cz);
        const unsigned long long bw = __ballot(cw);
        const unsigned long long ball = bx | by | bz | bw;
        unsigned B = 0u;
        if (ball) {
            const int L = __ffsll((long long)ball) - 1;
            const unsigned long long m = 1ull << L;
            B = 4u * (unsigned)L + ((bx & m) ? 0u : (by & m) ? 1u : (bz & m) ? 2u : 3u);
        }
        T4[r] = (B == 0u) ? 0.0f : __uint_as_float((B + BIN_OFF) << 17);
    }

    // --- EARLY bulk store of provable zeros (v < T4 <= kth); candidates
    //     skipped here (written exactly once, by fixup) + collected to LDS ---
#pragma unroll
    for (int i = 0; i < PER_T; ++i) {
#pragma unroll
        for (int r = 0; r < ROWS; ++r) {
            const float v = acc[i][r];
            if (v < T4[r]) {
                const int br = b0 + r;
                if (br < batch)
                    out[(size_t)br * OUT_F + t + i * THREADS] = 0.0f;
            } else {
                const unsigned idx = atomicAdd(&s_cnt[r], 1u);
                if (idx < CAND_CAP) s_cand[r][idx] = v;
            }
        }
    }
    bar_nodrain();                                 // C (stores ride through)

    // --- overflow fallback: exact uint bisection on count(>=x) ---
    unsigned ovf = 0;
#pragma unroll
    for (int r = 0; r < ROWS; ++r)
        if (s_cnt[r] > CAND_CAP) ovf |= (1u << r);

    if (ovf) {
        unsigned lo[ROWS], hi[ROWS];
#pragma unroll
        for (int r = 0; r < ROWS; ++r) {
            lo[r] = __float_as_uint(T4[r]);        // count(>=lo) >= k
            hi[r] = 0x41000000u;                   // 8.0f: count(>=hi)==0
        }
        for (int it = 0; it < 34; ++it) {
            unsigned work = 0;
#pragma unroll
            for (int r = 0; r < ROWS; ++r)
                if (((ovf >> r) & 1u) && hi[r] - lo[r] > 1u) work |= (1u << r);
            if (!work) break;
            unsigned mid[ROWS];
#pragma unroll
            for (int r = 0; r < ROWS; ++r) mid[r] = lo[r] + (hi[r] - lo[r]) / 2u;
            int c0 = 0, c1 = 0, c2 = 0, c3 = 0;
#pragma unroll
            for (int i = 0; i < PER_T; ++i) {
                c0 += (__float_as_uint(acc[i].x) >= mid[0]);
                c1 += (__float_as_uint(acc[i].y) >= mid[1]);
                c2 += (__float_as_uint(acc[i].z) >= mid[2]);
                c3 += (__float_as_uint(acc[i].w) >= mid[3]);
            }
#pragma unroll
            for (int d = 1; d < 64; d <<= 1) {
                c0 += __shfl_xor(c0, d);
                c1 += __shfl_xor(c1, d);
                c2 += __shfl_xor(c2, d);
                c3 += __shfl_xor(c3, d);
            }
            if (lane == 0) {
                s_pc[0][wave] = c0; s_pc[1][wave] = c1;
                s_pc[2][wave] = c2; s_pc[3][wave] = c3;
            }
            bar_nodrain();
#pragma unroll
            for (int r = 0; r < ROWS; ++r) {
                if ((work >> r) & 1u) {
                    int c = 0;
#pragma unroll
                    for (int w = 0; w < NWAVES; ++w) c += s_pc[r][w];
                    if (c >= k0) lo[r] = mid[r]; else hi[r] = mid[r];
                }
            }
            bar_nodrain();
        }
        if (t == 0) {
#pragma unroll
            for (int r = 0; r < ROWS; ++r)
                if ((ovf >> r) & 1u) s_kth[r] = __uint_as_float(lo[r]);
        }
    }

    // --- exact rank select over candidates: wave r -> row r ---
    if (wave < ROWS && !((ovf >> wave) & 1u)) {
        const unsigned c = s_cnt[wave];
        for (unsigned s = lane; s < c; s += 64) {
            const float v = s_cand[wave][s];
            int gt = 0, eq = 0;
            for (unsigned j = 0; j < c; ++j) {
                const float u = s_cand[wave][j];
                gt += (u > v);
                eq += (u == v);
            }
            if (gt < k0 && gt + eq >= k0) s_kth[wave] = v;   // ties: same value
        }
    }
    bar_nodrain();                                 // D (stores ride through)
    const float4v kth4 = { s_kth[0], s_kth[1], s_kth[2], s_kth[3] };

    // --- fixup: store the skipped candidates (v >= T4), exactly once ---
#pragma unroll
    for (int i = 0; i < PER_T; ++i) {
#pragma unroll
        for (int r = 0; r < ROWS; ++r) {
            const float v = acc[i][r];
            if (v >= T4[r]) {
                const int br = b0 + r;
                if (br < batch)
                    out[(size_t)br * OUT_F + t + i * THREADS]
                        = (v >= kth4[r]) ? v : 0.0f;
            }
        }
    }
}

extern "C" void kernel_launch(void* const* d_in, const int* in_sizes, int n_in,
                              void* d_out, int out_size, void* d_ws, size_t ws_size,
                              hipStream_t stream) {
    const float* inp  = (const float*)d_in[0];
    const int*   proj = (const int*)d_in[1];
    const int*   hlen = (const int*)d_in[2];
    float*       out  = (float*)d_out;

    const int batch  = in_sizes[0] / IN_F;            // 4096
    const int blocks = (batch + ROWS - 1) / ROWS;     // 1024

    hipLaunchKernelGGL(flyhash_wta_kernel, dim3(blocks), dim3(THREADS), 0, stream,
                       inp, proj, hlen, out, batch);
}

// Round 13
// 52.957 us; speedup vs baseline: 1.9500x; 1.9500x over previous
//
#include <hip/hip_runtime.h>

#define IN_F     512
#define OUT_F    10240
#define NPROJ    6
#define THREADS  512
#define PER_T    (OUT_F / THREADS)   // 20 outputs per thread
#define ROWS     4                   // batch rows per block
#define NBINS    256
#define CAND_CAP 128
#define NWAVES   (THREADS / 64)
#define BIN_OFF  8064u               // (bits>>17) of 0.5f; bins cover [0.5, 8)

typedef float    float4v __attribute__((ext_vector_type(4)));
typedef unsigned uint4v  __attribute__((ext_vector_type(4)));

// Round-10 kernel, reinstated verbatim (best clean result: 52.8 µs).
// One block = 4 batch rows; static-bit-bin selection.
// bin(v) = clamp((float_bits(v) >> 17) - 8064, 0, 255): monotone for v >= 0,
// bin edges are exact float thresholds -> no block-max reduce, no T-min
// reduce, no data-dependent scaling. Selection: per-thread max -> 512-max
// static histogram (4 atomics/thread) -> suffix scan -> T = lower edge of
// the bin holding the k-th largest thread-max (provably <= kth value) ->
// collect candidates >= T -> exact rank select on original values.
// Fallback (bin-0 rows / overflow): exact uint bisection on count(>=x).
__global__ __launch_bounds__(THREADS, 4) void flyhash_wta_kernel(
    const float* __restrict__ inp,
    const int*   __restrict__ proj,
    const int*   __restrict__ hlen,
    float*       __restrict__ out,
    int batch)
{
    __shared__ float4v  s_rowT[IN_F];             // 8 KB transposed tile
    __shared__ unsigned s_hist[ROWS][NBINS];      // 4 KB thread-max histogram
    __shared__ unsigned s_bin[ROWS];
    __shared__ float    s_cand[ROWS][CAND_CAP];   // 2 KB
    __shared__ unsigned s_cnt[ROWS];
    __shared__ float    s_kth[ROWS];
    __shared__ int      s_pc[ROWS][NWAVES];       // bisection partial counts

    const int t    = threadIdx.x;
    const int lane = t & 63;
    const int wave = t >> 6;
    const int b0   = blockIdx.x * ROWS;

    // --- stage 4 rows transposed (linear LDS writes); zero select state ---
    {
        const int r  = t & 3;
        const int cb = t >> 2;
        int br = b0 + r;
        if (br >= batch) br = batch - 1;           // clamp (reads only)
        const float* g = inp + (size_t)br * IN_F;
#pragma unroll
        for (int p = 0; p < 4; ++p) {
            const int c = cb + p * (THREADS / 4);
            ((float*)s_rowT)[c * 4 + r] = g[c];
        }
    }
    ((unsigned*)s_hist)[t]           = 0u;
    ((unsigned*)s_hist)[t + THREADS] = 0u;
    if (t < ROWS) { s_cnt[t] = 0u; s_kth[t] = 0.0f; }
    __syncthreads();

    const int k0 = hlen[0];

    // --- gather: one ds_read_b128 per index serves all 4 rows (round-4) ---
    float4v acc[PER_T];
#pragma unroll
    for (int i = 0; i < PER_T; ++i) {
        const int o = t + i * THREADS;
        const int2* ip = (const int2*)(proj + (size_t)o * NPROJ);
        const int2 p0 = ip[0];
        const int2 p1 = ip[1];
        const int2 p2 = ip[2];
        // same per-component summation order as rounds 1-9 (absmax 0)
        const float4v a01 = s_rowT[p0.x] + s_rowT[p0.y];
        const float4v a23 = s_rowT[p1.x] + s_rowT[p1.y];
        const float4v a45 = s_rowT[p2.x] + s_rowT[p2.y];
        acc[i] = (a01 + a23) + a45;
    }

    // --- per-thread per-row max ---
    float4v tmax = acc[0];
#pragma unroll
    for (int i = 1; i < PER_T; ++i) {
        tmax.x = fmaxf(tmax.x, acc[i].x);
        tmax.y = fmaxf(tmax.y, acc[i].y);
        tmax.z = fmaxf(tmax.z, acc[i].z);
        tmax.w = fmaxf(tmax.w, acc[i].w);
    }

    // --- static-bit histogram of thread-maxes: 4 atomics/thread, no reduce ---
#pragma unroll
    for (int r = 0; r < ROWS; ++r) {
        int key = (int)(__float_as_uint(tmax[r]) >> 17) - (int)BIN_OFF;
        key = key < 0 ? 0 : (key > NBINS - 1 ? NBINS - 1 : key);
        atomicAdd(&s_hist[r][key], 1u);
    }
    __syncthreads();

    // --- suffix scan on max-histogram: wave r -> row r (lane holds 4 bins) ---
    if (wave < ROWS) {
        const uint4v h = ((const uint4v*)&s_hist[wave][0])[lane];
        const unsigned s3 = h.w;
        const unsigned s2 = h.z + s3;
        const unsigned s1 = h.y + s2;
        const unsigned s0 = h.x + s1;
        unsigned T = s0;
#pragma unroll
        for (int d = 1; d < 64; d <<= 1) {
            const unsigned o = __shfl_down(T, d);
            if (lane + d < 64) T += o;
        }
        const unsigned A = T - s0;                 // sum over lanes > lane
        const unsigned S0 = A + s0, S1 = A + s1, S2 = A + s2, S3 = A + s3;
        if (h.x && (int)S0 >= k0 && (int)(S0 - h.x) < k0) s_bin[wave] = 4u * lane + 0u;
        if (h.y && (int)S1 >= k0 && (int)(S1 - h.y) < k0) s_bin[wave] = 4u * lane + 1u;
        if (h.z && (int)S2 >= k0 && (int)(S2 - h.z) < k0) s_bin[wave] = 4u * lane + 2u;
        if (h.w && (int)S3 >= k0 && (int)(S3 - h.w) < k0) s_bin[wave] = 4u * lane + 3u;
        if (lane == 0 && (int)(A + s0) < k0) s_bin[wave] = 0u;   // k > #maxes
    }
    __syncthreads();

    // --- T4[r] = exact lower edge of selected bin (<= kth value of row) ---
    float4v T4;
#pragma unroll
    for (int r = 0; r < ROWS; ++r) {
        const unsigned B = s_bin[r];
        T4[r] = (B == 0u) ? 0.0f : __uint_as_float((B + BIN_OFF) << 17);
    }

    // --- collect candidates >= T (sparse atomics; exact original values) ---
#pragma unroll
    for (int i = 0; i < PER_T; ++i) {
#pragma unroll
        for (int r = 0; r < ROWS; ++r) {
            const float v = acc[i][r];
            if (v >= T4[r]) {
                const unsigned idx = atomicAdd(&s_cnt[r], 1u);
                if (idx < CAND_CAP) s_cand[r][idx] = v;
            }
        }
    }
    __syncthreads();

    // --- overflow fallback: exact uint bisection on count(>=x) ---
    unsigned ovf = 0;
#pragma unroll
    for (int r = 0; r < ROWS; ++r)
        if (s_cnt[r] > CAND_CAP) ovf |= (1u << r);

    if (ovf) {
        unsigned lo[ROWS], hi[ROWS];
#pragma unroll
        for (int r = 0; r < ROWS; ++r) {
            lo[r] = __float_as_uint(T4[r]);        // count(>=lo) >= k
            hi[r] = 0x41000000u;                   // 8.0f: count(>=hi)==0 (acts < 6)
        }
        for (int it = 0; it < 34; ++it) {
            unsigned work = 0;
#pragma unroll
            for (int r = 0; r < ROWS; ++r)
                if (((ovf >> r) & 1u) && hi[r] - lo[r] > 1u) work |= (1u << r);
            if (!work) break;
            unsigned mid[ROWS];
#pragma unroll
            for (int r = 0; r < ROWS; ++r) mid[r] = lo[r] + (hi[r] - lo[r]) / 2u;
            int c0 = 0, c1 = 0, c2 = 0, c3 = 0;
#pragma unroll
            for (int i = 0; i < PER_T; ++i) {
                c0 += (__float_as_uint(acc[i].x) >= mid[0]);
                c1 += (__float_as_uint(acc[i].y) >= mid[1]);
                c2 += (__float_as_uint(acc[i].z) >= mid[2]);
                c3 += (__float_as_uint(acc[i].w) >= mid[3]);
            }
#pragma unroll
            for (int d = 1; d < 64; d <<= 1) {
                c0 += __shfl_xor(c0, d);
                c1 += __shfl_xor(c1, d);
                c2 += __shfl_xor(c2, d);
                c3 += __shfl_xor(c3, d);
            }
            if (lane == 0) {
                s_pc[0][wave] = c0; s_pc[1][wave] = c1;
                s_pc[2][wave] = c2; s_pc[3][wave] = c3;
            }
            __syncthreads();
#pragma unroll
            for (int r = 0; r < ROWS; ++r) {
                if ((work >> r) & 1u) {
                    int c = 0;
#pragma unroll
                    for (int w = 0; w < NWAVES; ++w) c += s_pc[r][w];
                    if (c >= k0) lo[r] = mid[r]; else hi[r] = mid[r];
                }
            }
            __syncthreads();
        }
        if (t == 0) {
#pragma unroll
            for (int r = 0; r < ROWS; ++r)
                if ((ovf >> r) & 1u) s_kth[r] = __uint_as_float(lo[r]);
        }
    }

    // --- exact rank select over candidates: wave r -> row r ---
    if (wave < ROWS && !((ovf >> wave) & 1u)) {
        const unsigned c = s_cnt[wave];
        for (unsigned s = lane; s < c; s += 64) {
            const float v = s_cand[wave][s];
            int gt = 0, eq = 0;
            for (unsigned j = 0; j < c; ++j) {
                const float u = s_cand[wave][j];
                gt += (u > v);
                eq += (u == v);
            }
            if (gt < k0 && gt + eq >= k0) s_kth[wave] = v;   // ties write same value
        }
    }
    __syncthreads();
    const float4v kth4 = { s_kth[0], s_kth[1], s_kth[2], s_kth[3] };

    // --- predicated coalesced stores (round-4 layout) ---
#pragma unroll
    for (int r = 0; r < ROWS; ++r) {
        const int br = b0 + r;
        if (br < batch) {
            float* orow = out + (size_t)br * OUT_F;
#pragma unroll
            for (int i = 0; i < PER_T; ++i) {
                const float v = acc[i][r];
                orow[t + i * THREADS] = (v >= kth4[r]) ? v : 0.0f;
            }
        }
    }
}

extern "C" void kernel_launch(void* const* d_in, const int* in_sizes, int n_in,
                              void* d_out, int out_size, void* d_ws, size_t ws_size,
                              hipStream_t stream) {
    const float* inp  = (const float*)d_in[0];
    const int*   proj = (const int*)d_in[1];
    const int*   hlen = (const int*)d_in[2];
    float*       out  = (float*)d_out;

    const int batch  = in_sizes[0] / IN_F;            // 4096
    const int blocks = (batch + ROWS - 1) / ROWS;     // 1024

    hipLaunchKernelGGL(flyhash_wta_kernel, dim3(blocks), dim3(THREADS), 0, stream,
                       inp, proj, hlen, out, batch);
}